// Round 1
// 457.372 us; speedup vs baseline: 1.2249x; 1.2249x over previous
//
#include <hip/hip_runtime.h>
#include <hip/hip_bf16.h>

// ---------------------------------------------------------------------------
// HybridGATLSTM on MI355X — round 7.
//   Key change: LSTM (16 blocks, latency-bound) and GAT (1536 graphs) are
//   dataflow-independent until the heads, but ran sequentially because LSTM
//   Pre scratch lived in the attn2 output region. Round 7 fuses them into ONE
//   kernel: blocks 0..15 = LSTM (Pre scratch in workspace), blocks 16..1551 =
//   GAT prep+write fused (stats stay in LDS, adj mask from LDS, full tile
//   written by the same block). LSTM waves run at s_setprio(1) since they are
//   the critical path. Union'd LDS 55KB -> 2 blocks/CU.
//   Fallback (ws too small): sequential lstm -> fused gat -> heads (still
//   saves the stats round-trip vs round 6).
// ---------------------------------------------------------------------------

typedef _Float16 half8 __attribute__((ext_vector_type(8)));
typedef float floatx4 __attribute__((ext_vector_type(4)));
typedef float float4v __attribute__((ext_vector_type(4)));

#define LOG2E 1.44269504088896f

__device__ __forceinline__ float fast_exp(float x) {
    return __builtin_amdgcn_exp2f(x * LOG2E);
}
__device__ __forceinline__ float sigm(float x) {
    x = fminf(fmaxf(x, -30.f), 30.f);
    return __builtin_amdgcn_rcpf(1.f + __builtin_amdgcn_exp2f(-x * LOG2E));
}
__device__ __forceinline__ float tanhp(float x) {
    x = fminf(fmaxf(x, -15.f), 15.f);
    float e = __builtin_amdgcn_exp2f(-2.f * LOG2E * x);
    return (1.f - e) * __builtin_amdgcn_rcpf(1.f + e);
}
__device__ __forceinline__ void split8v(float4v v0, float4v v1, half8& hi, half8& lo) {
#pragma unroll
    for (int j = 0; j < 4; ++j) {
        _Float16 h = (_Float16)v0[j];
        hi[j] = h; lo[j] = (_Float16)(v0[j] - (float)h);
    }
#pragma unroll
    for (int j = 0; j < 4; ++j) {
        _Float16 h = (_Float16)v1[j];
        hi[4 + j] = h; lo[4 + j] = (_Float16)(v1[j] - (float)h);
    }
}

// ---------------------------------------------------------------------------
// Shared-memory layouts (union'd in the fused kernel)
// ---------------------------------------------------------------------------
struct LstmSh {
    float hbuf[2][544];     // 2 buffers x 4 bank-shifted copies(136)
    float Hseq[96 * 132];   // layer output sequence (padded rows)
};
struct GatSh {
    unsigned char adjb[128 * 132];
    float xv[128];
    float u1[32], v1[32], coef[4];
    float s1v[128];
    float h2s[128 * 33];
    float wh2[128 * 17];
    float Lv[128], Rv[128], mx2[128], rd2[128];
    float m_h[4][128], d_h[4][128], s_h[4][128];
};
union ShU { LstmSh l; GatSh g; };

// ---------------------------------------------------------------------------
// LSTM body: one block per batch element, 512 threads. Same structure as
// round 6 (MFMA proj GEMM + fp32 VALU recurrence, 1 barrier/step).
// ---------------------------------------------------------------------------
__device__ __forceinline__ void lstm_body(LstmSh& sh, int b,
    const float* __restrict__ x,     // [16][96][128]
    const float* __restrict__ Wih,   // [3][512][128]
    const float* __restrict__ Whh,   // [3][512][128]
    const float* __restrict__ bih,   // [3][512]
    const float* __restrict__ bhh,   // [3][512]
    float* __restrict__ PreBase,     // this block: 3 * 96*512 floats
    float* __restrict__ xl_out)      // [16][128]
{
    int tid = threadIdx.x;
    int w = tid >> 6, lane = tid & 63, quad = lane >> 4, sub = lane & 15;

    // rec decomposition: hu = 16w + sub, K-chunk c = quad (32 K each)
    int hu = 16 * w + sub;
    int c4 = quad;

    __builtin_amdgcn_s_setprio(1);   // LSTM is the critical path when fused

    for (int layer = 0; layer < 3; ++layer) {
        const float* WihL = Wih + layer * 65536;
        const float* WhhL = Whh + layer * 65536;
        float* Pre = PreBase + layer * (96 * 512);

        // ======== proj GEMM (MFMA, split-fp16): Pre[t][r] = A[t].Wih[r]+bias
        {
            half8 bhi[4][4], blo[4][4];
            float bias[4];
#pragma unroll
            for (int tt = 0; tt < 4; ++tt) {
                int r = tt * 128 + 16 * w + sub;
                bias[tt] = bih[layer * 512 + r] + bhh[layer * 512 + r];
#pragma unroll
                for (int kc = 0; kc < 4; ++kc) {
                    const float4v* p = (const float4v*)(WihL + r * 128 + kc * 32 + quad * 8);
                    split8v(p[0], p[1], bhi[tt][kc], blo[tt][kc]);
                }
            }
            for (int mt = 0; mt < 6; ++mt) {
                half8 ahi[4], alo[4];
                if (layer == 0) {
                    const float* arow = x + b * 12288 + (mt * 16 + sub) * 128;
#pragma unroll
                    for (int kc = 0; kc < 4; ++kc) {
                        const float4v* p = (const float4v*)(arow + kc * 32 + quad * 8);
                        split8v(p[0], p[1], ahi[kc], alo[kc]);
                    }
                } else {
                    const float* arow = sh.Hseq + (mt * 16 + sub) * 132;
#pragma unroll
                    for (int kc = 0; kc < 4; ++kc) {
                        const float4v* p = (const float4v*)(arow + kc * 32 + quad * 8);
                        split8v(p[0], p[1], ahi[kc], alo[kc]);
                    }
                }
                floatx4 acc[4];
#pragma unroll
                for (int tt = 0; tt < 4; ++tt) {
                    floatx4 a = {bias[tt], bias[tt], bias[tt], bias[tt]};
                    acc[tt] = a;
                }
#pragma unroll
                for (int tt = 0; tt < 4; ++tt)
#pragma unroll
                    for (int kc = 0; kc < 4; ++kc) {
                        acc[tt] = __builtin_amdgcn_mfma_f32_16x16x32_f16(ahi[kc], bhi[tt][kc], acc[tt], 0, 0, 0);
                        acc[tt] = __builtin_amdgcn_mfma_f32_16x16x32_f16(ahi[kc], blo[tt][kc], acc[tt], 0, 0, 0);
                        acc[tt] = __builtin_amdgcn_mfma_f32_16x16x32_f16(alo[kc], bhi[tt][kc], acc[tt], 0, 0, 0);
                    }
                // store: timestep m = mt*16 + quad*4 + reg, row = tt*128+16w+sub
#pragma unroll
                for (int tt = 0; tt < 4; ++tt)
#pragma unroll
                    for (int reg = 0; reg < 4; ++reg)
                        Pre[(mt * 16 + quad * 4 + reg) * 512 + tt * 128 + 16 * w + sub] = acc[tt][reg];
            }
        }

        // ======== recurrence weights: 4 gate rows of hu, K in [32c, 32c+32)
        // 4 x 8 x float4 = 128 VGPRs (must not exceed this: spill cliff)
        float4v wgt[4][8];
#pragma unroll
        for (int g = 0; g < 4; ++g) {
            const float4v* p = (const float4v*)(WhhL + (g * 128 + hu) * 128 + c4 * 32);
#pragma unroll
            for (int k = 0; k < 8; ++k) wgt[g][k] = p[k];
        }
        sh.hbuf[0][c4 * 136 + hu] = 0.f;   // zero all 4 copies of buffer 0
        float cvar = 0.f;
        __syncthreads();   // Pre stores drained; hbuf zeroed; Hseq reads done

        for (int t = 0; t < 96; ++t) {
            int rb = t & 1, wb = rb ^ 1;
            // Pre loads issued early (L2-resident), consumed after butterfly
            float pre[4];
#pragma unroll
            for (int g = 0; g < 4; ++g)
                pre[g] = Pre[t * 512 + g * 128 + hu];

            // h chunk from this lane's bank-shifted copy: banks (8c+4k)%32,
            // distinct across c for fixed k -> conflict-free broadcast
            const float4v* hc = (const float4v*)(&sh.hbuf[rb][c4 * 168]);
            float4v p4[4];
#pragma unroll
            for (int g = 0; g < 4; ++g) {
                float4v z = {0.f, 0.f, 0.f, 0.f};
                p4[g] = z;
            }
#pragma unroll
            for (int k = 0; k < 8; ++k) {
                float4v hv = hc[k];
#pragma unroll
                for (int g = 0; g < 4; ++g) p4[g] += wgt[g][k] * hv;
            }
            float p[4];
#pragma unroll
            for (int g = 0; g < 4; ++g) {
                float s = p4[g].x + p4[g].y + p4[g].z + p4[g].w;
                s += __shfl_xor(s, 16, 64);   // combine chunk pairs
                s += __shfl_xor(s, 32, 64);   // combine halves
                p[g] = s + pre[g];
            }
            // all 4 c-lanes compute identical activations (keeps cvar coherent)
            float c = sigm(p[1]) * cvar + sigm(p[0]) * tanhp(p[2]);
            cvar = c;
            float h = sigm(p[3]) * tanhp(c);
            sh.hbuf[wb][c4 * 136 + hu] = h;      // each lane updates its copy
            if (c4 == 0) {
                if (layer < 2) sh.Hseq[t * 132 + hu] = h;
                else if (t == 95) xl_out[b * 128 + hu] = h;
            }
            __syncthreads();   // h visible; all reads of rb complete
        }
        __syncthreads();
    }
    __builtin_amdgcn_s_setprio(0);
}

// ---------------------------------------------------------------------------
// GAT body: one block per graph (b,s), 512 threads. prep + full tile write
// fused — stats never leave LDS, adj mask served from staged LDS bytes.
// ---------------------------------------------------------------------------
__device__ __forceinline__ void gat_body(GatSh& s, int m,
    const float* __restrict__ x, const float* __restrict__ adj,
    const float* __restrict__ W_emb, const float* __restrict__ b_emb,
    const float* __restrict__ W1, const float* __restrict__ a1,
    const float* __restrict__ W2, const float* __restrict__ a2,
    float* __restrict__ attn_out, float* __restrict__ xg)
{
    int tid = threadIdx.x;

    if (tid < 128) s.xv[tid] = x[m * 128 + tid];
    for (int idx = tid; idx < 16384; idx += 512) {
        int i = idx >> 7, j = idx & 127;
        s.adjb[i * 132 + j] = adj[idx] > 0.f ? 1 : 0;
    }
    if (tid < 32) {
        float su = 0.f, sv = 0.f;
        for (int kk = 0; kk < 32; ++kk) {
            su += W_emb[kk] * W1[kk * 32 + tid];
            sv += b_emb[kk] * W1[kk * 32 + tid];
        }
        s.u1[tid] = su; s.v1[tid] = sv;
    }
    __syncthreads();
    if (tid < 4) {
        const float* av = a1 + ((tid >= 2) ? 32 : 0);
        const float* uv = (tid & 1) ? s.v1 : s.u1;
        float sum = 0.f;
        for (int f = 0; f < 32; ++f) sum += uv[f] * av[f];
        s.coef[tid] = sum;
    }
    __syncthreads();
    float cL = s.coef[0], dL = s.coef[1], cR = s.coef[2], dR = s.coef[3];

    // GAT1 softmax stats + weighted scalar sum (FI=1 collapse): 4 j-quarters
    {
        int i = tid & 127, qf = tid >> 7;
        float Li = s.xv[i] * cL + dL;
        int j0 = qf * 32;
        float mmax = -3.0e38f;
        for (int j = j0; j < j0 + 32; ++j) {
            if (s.adjb[i * 132 + j]) {
                float e = Li + s.xv[j] * cR + dR;
                e = e > 0.f ? e : 0.2f * e;
                mmax = fmaxf(mmax, e);
            }
        }
        float den = 0.f, wsum = 0.f;
        for (int j = j0; j < j0 + 32; ++j) {
            if (s.adjb[i * 132 + j]) {
                float e = Li + s.xv[j] * cR + dR;
                e = e > 0.f ? e : 0.2f * e;
                float p = fast_exp(e - mmax);
                den += p; wsum += p * s.xv[j];
            }
        }
        s.m_h[qf][i] = mmax; s.d_h[qf][i] = den; s.s_h[qf][i] = wsum;
    }
    __syncthreads();
    if (tid < 128) {
        int i = tid;
        float mm = fmaxf(fmaxf(s.m_h[0][i], s.m_h[1][i]),
                         fmaxf(s.m_h[2][i], s.m_h[3][i]));
        float den = 0.f, wsum = 0.f;
#pragma unroll
        for (int q = 0; q < 4; ++q) {
            float sc = fast_exp(s.m_h[q][i] - mm);
            den += s.d_h[q][i] * sc; wsum += s.s_h[q][i] * sc;
        }
        s.s1v[i] = wsum / den;
    }
    __syncthreads();
    // h2 = elu(s1*u1 + v1)
    for (int e = tid; e < 4096; e += 512) {
        int i = e >> 5, f = e & 31;
        float v = s.s1v[i] * s.u1[f] + s.v1[f];
        s.h2s[i * 33 + f] = v > 0.f ? v : fast_exp(v) - 1.f;
    }
    __syncthreads();
    // Wh2 = h2 @ W2 (128x32 @ 32x16), 4 threads per row
    {
        int i = tid >> 2, g0 = (tid & 3) * 4;
        float accv[4] = {0.f, 0.f, 0.f, 0.f};
        for (int f = 0; f < 32; ++f) {
            float hv = s.h2s[i * 33 + f];
#pragma unroll
            for (int g = 0; g < 4; ++g) accv[g] += hv * W2[f * 16 + g0 + g];
        }
#pragma unroll
        for (int g = 0; g < 4; ++g) s.wh2[i * 17 + g0 + g] = accv[g];
    }
    __syncthreads();
    if (tid < 256) {
        int i = tid & 127, which = tid >> 7;
        const float* aa = a2 + which * 16;
        float sum = 0.f;
        for (int g = 0; g < 16; ++g) sum += s.wh2[i * 17 + g] * aa[g];
        (which ? s.Rv : s.Lv)[i] = sum;
    }
    __syncthreads();
    // attn2 softmax stats: 4 j-quarters
    {
        int i = tid & 127, qf = tid >> 7;
        float Li = s.Lv[i];
        int j0 = qf * 32;
        float mmax = -3.0e38f;
        for (int j = j0; j < j0 + 32; ++j) {
            if (s.adjb[i * 132 + j]) {
                float e = Li + s.Rv[j];
                e = e > 0.f ? e : 0.2f * e;
                mmax = fmaxf(mmax, e);
            }
        }
        float den = 0.f;
        for (int j = j0; j < j0 + 32; ++j) {
            if (s.adjb[i * 132 + j]) {
                float e = Li + s.Rv[j];
                e = e > 0.f ? e : 0.2f * e;
                den += fast_exp(e - mmax);
            }
        }
        s.m_h[qf][i] = mmax; s.d_h[qf][i] = den;
    }
    __syncthreads();
    if (tid < 128) {
        int i = tid;
        float mm = fmaxf(fmaxf(s.m_h[0][i], s.m_h[1][i]),
                         fmaxf(s.m_h[2][i], s.m_h[3][i]));
        float den = 0.f;
#pragma unroll
        for (int q = 0; q < 4; ++q) den += s.d_h[q][i] * fast_exp(s.m_h[q][i] - mm);
        s.mx2[i] = mm; s.rd2[i] = 1.0f / den;
    }
    __syncthreads();

    // out2 = attn2 @ Wh2 only for the last timestep of each batch
    if (m % 96 == 95) {
        int b = m / 96;
        int i = tid >> 2, g0 = (tid & 3) * 4;
        float accv[4] = {0.f, 0.f, 0.f, 0.f};
        for (int j = 0; j < 128; ++j) {
            float p = 0.f;
            if (s.adjb[i * 132 + j]) {
                float e = s.Lv[i] + s.Rv[j];
                e = e > 0.f ? e : 0.2f * e;
                p = fast_exp(e - s.mx2[i]) * s.rd2[i];
            }
#pragma unroll
            for (int g = 0; g < 4; ++g) accv[g] += p * s.wh2[j * 17 + g0 + g];
        }
#pragma unroll
        for (int g = 0; g < 4; ++g) xg[b * 2048 + i * 16 + g0 + g] = accv[g];
    }

    // full 16384-float tile write (float4), mask from LDS adjb
    float* aout = attn_out + m * 16384;
#pragma unroll 4
    for (int k = 0; k < 8; ++k) {
        int e0 = k * 2048 + tid * 4;
        int i = e0 >> 7, j0 = e0 & 127;
        float Li = s.Lv[i], mi = s.mx2[i], ri = s.rd2[i];
        const unsigned char* ab = &s.adjb[i * 132 + j0];
        float4v p;
#pragma unroll
        for (int u = 0; u < 4; ++u) {
            float pv = 0.f;
            if (ab[u]) {
                float e = Li + s.Rv[j0 + u];
                e = e > 0.f ? e : 0.2f * e;
                pv = fast_exp(e - mi) * ri;
            }
            p[u] = pv;
        }
        *(float4v*)(aout + e0) = p;
    }
}

// ---------------------------------------------------------------------------
// Fused kernel: blocks 0..15 LSTM, 16..1551 GAT.
// ---------------------------------------------------------------------------
__global__ __launch_bounds__(512, 2) void fused_kernel(
    const float* __restrict__ x, const float* __restrict__ adj,
    const float* __restrict__ W_emb, const float* __restrict__ b_emb,
    const float* __restrict__ W1, const float* __restrict__ a1,
    const float* __restrict__ W2, const float* __restrict__ a2,
    const float* __restrict__ Wih, const float* __restrict__ Whh,
    const float* __restrict__ bih, const float* __restrict__ bhh,
    float* __restrict__ Pre, float* __restrict__ xl_out,
    float* __restrict__ attn_out, float* __restrict__ xg)
{
    __shared__ ShU sh;
    int bb = blockIdx.x;
    if (bb < 16) {
        lstm_body(sh.l, bb, x, Wih, Whh, bih, bhh, Pre + bb * 147456, xl_out);
    } else {
        gat_body(sh.g, bb - 16, x, adj, W_emb, b_emb, W1, a1, W2, a2, attn_out, xg);
    }
}

// ---------------------------------------------------------------------------
// Fallback standalone kernels (ws too small for Pre): sequential as round 6.
// ---------------------------------------------------------------------------
__global__ __launch_bounds__(512, 2) void lstm_batch_kernel(
    const float* __restrict__ x, const float* __restrict__ Wih,
    const float* __restrict__ Whh, const float* __restrict__ bih,
    const float* __restrict__ bhh, float* __restrict__ scratch,
    float* __restrict__ xl_out)
{
    __shared__ LstmSh sh;
    int b = blockIdx.x;
    lstm_body(sh, b, x, Wih, Whh, bih, bhh, scratch + b * 147456, xl_out);
}

__global__ __launch_bounds__(512, 2) void gat_kernel(
    const float* __restrict__ x, const float* __restrict__ adj,
    const float* __restrict__ W_emb, const float* __restrict__ b_emb,
    const float* __restrict__ W1, const float* __restrict__ a1,
    const float* __restrict__ W2, const float* __restrict__ a2,
    float* __restrict__ attn_out, float* __restrict__ xg)
{
    __shared__ GatSh sh;
    gat_body(sh, blockIdx.x, x, adj, W_emb, b_emb, W1, a1, W2, a2, attn_out, xg);
}

// ---------------------------------------------------------------------------
// Heads (unchanged)
// ---------------------------------------------------------------------------
__global__ __launch_bounds__(256) void head_partial_kernel(
    const float* __restrict__ xl, const float* __restrict__ xg,
    const float* __restrict__ W1, float* __restrict__ hp)
{
    int k = blockIdx.x >> 4, chunk = blockIdx.x & 15;
    int d = threadIdx.x & 63, bg = threadIdx.x >> 6;
    float acc[4] = {0.f, 0.f, 0.f, 0.f};
    int c0 = chunk * 136;
    for (int cc = c0; cc < c0 + 136; ++cc) {
        float wv = W1[(k * 2176 + cc) * 64 + d];
#pragma unroll
        for (int u = 0; u < 4; ++u) {
            int b = bg * 4 + u;
            float cv = (cc < 128) ? xl[b * 128 + cc] : xg[b * 2048 + cc - 128];
            acc[u] += wv * cv;
        }
    }
#pragma unroll
    for (int u = 0; u < 4; ++u)
        hp[(((k * 16 + chunk) * 16) + bg * 4 + u) * 64 + d] = acc[u];
}

__global__ __launch_bounds__(256) void head_final_kernel(
    const float* __restrict__ hp, const float* __restrict__ b1,
    const float* __restrict__ W2, const float* __restrict__ b2,
    const float* __restrict__ W3d, const float* __restrict__ b3d,
    const float* __restrict__ W3r, const float* __restrict__ b3r,
    const float* __restrict__ W3v, const float* __restrict__ b3v,
    float* __restrict__ out)
{
    __shared__ float h1s[3 * 16 * 64];
    __shared__ float h2s[3 * 16 * 32];
    int tid = threadIdx.x;
    for (int o = tid; o < 3072; o += 256) {
        int k = o >> 10, rem = o & 1023, b = rem >> 6, d = rem & 63;
        float s = b1[k * 64 + d];
        for (int ch = 0; ch < 16; ++ch)
            s += hp[(((k * 16 + ch) * 16) + b) * 64 + d];
        h1s[o] = fmaxf(s, 0.f);
    }
    __syncthreads();
    for (int o = tid; o < 1536; o += 256) {
        int k = o >> 9, rem = o & 511, b = rem >> 5, e = rem & 31;
        float s = b2[k * 32 + e];
        for (int dd = 0; dd < 64; ++dd)
            s += h1s[(k * 16 + b) * 64 + dd] * W2[(k * 64 + dd) * 32 + e];
        h2s[o] = fmaxf(s, 0.f);
    }
    __syncthreads();
    if (tid < 64) {
        if (tid < 16) {
            int b = tid; float s = b3d[0];
            for (int e = 0; e < 32; ++e) s += h2s[b * 32 + e] * W3d[e];
            out[b] = s;
        } else if (tid < 32) {
            int b = tid - 16; float s = b3r[0];
            for (int e = 0; e < 32; ++e) s += h2s[(16 + b) * 32 + e] * W3r[e];
            out[16 + b] = s;
        } else {
            int b = (tid - 32) >> 1, j = tid & 1; float s = b3v[j];
            for (int e = 0; e < 32; ++e) s += h2s[(32 + b) * 32 + e] * W3v[e * 2 + j];
            out[32 + b * 2 + j] = s;
        }
    }
}

// ---------------------------------------------------------------------------
extern "C" void kernel_launch(void* const* d_in, const int* in_sizes, int n_in,
                              void* d_out, int out_size, void* d_ws, size_t ws_size,
                              hipStream_t stream)
{
    const float* x     = (const float*)d_in[0];
    const float* adj   = (const float*)d_in[1];
    const float* W_emb = (const float*)d_in[2];
    const float* b_emb = (const float*)d_in[3];
    const float* W1    = (const float*)d_in[4];
    const float* a1    = (const float*)d_in[5];
    const float* W2    = (const float*)d_in[6];
    const float* a2    = (const float*)d_in[7];
    const float* Wih   = (const float*)d_in[8];
    const float* Whh   = (const float*)d_in[9];
    const float* bih   = (const float*)d_in[10];
    const float* bhh   = (const float*)d_in[11];
    const float* hW1   = (const float*)d_in[12];
    const float* hb1   = (const float*)d_in[13];
    const float* hW2   = (const float*)d_in[14];
    const float* hb2   = (const float*)d_in[15];
    const float* W3d   = (const float*)d_in[16];
    const float* b3d   = (const float*)d_in[17];
    const float* W3r   = (const float*)d_in[18];
    const float* b3r   = (const float*)d_in[19];
    const float* W3v   = (const float*)d_in[20];
    const float* b3v   = (const float*)d_in[21];

    float* out = (float*)d_out;

    float* wsf = (float*)d_ws;
    float* XG  = wsf;                   // 16*2048
    float* XL  = wsf + 32768;           // 16*128
    float* HP  = wsf + 34816;           // 3*16*16*64
    float* PRE = wsf + 83968;           // 16 * 3*96*512 (fused path only)

    // ws floats needed for the fused path (XG+XL+HP + Pre scratch)
    size_t need_bytes = (size_t)(83968 + 16 * 147456) * sizeof(float);

    if (ws_size >= need_bytes) {
        // Overlapped path: LSTM (blocks 0..15) + GAT (blocks 16..1551) in one
        // launch; Pre scratch in workspace so the attn2 region is free for
        // the concurrent GAT tile writes.
        fused_kernel<<<1552, 512, 0, stream>>>(
            x, adj, W_emb, b_emb, W1, a1, W2, a2,
            Wih, Whh, bih, bhh, PRE, XL, out + 64, XG);
    } else {
        // Fallback: sequential, Pre scratch in the attn2 region of d_out
        // (gat overwrites every tile afterwards).
        lstm_batch_kernel<<<16, 512, 0, stream>>>(x, Wih, Whh, bih, bhh, out + 64, XL);
        gat_kernel<<<1536, 512, 0, stream>>>(x, adj, W_emb, b_emb, W1, a1, W2, a2, out + 64, XG);
    }
    head_partial_kernel<<<48, 256, 0, stream>>>(XL, XG, hW1, HP);
    head_final_kernel<<<1, 256, 0, stream>>>(HP, hb1, hW2, hb2, W3d, b3d, W3r, b3r, W3v, b3v, out);
}